// Round 2
// baseline (730.595 us; speedup 1.0000x reference)
//
#include <hip/hip_runtime.h>

#define N_NODES_C 100000
#define N_EDGES_C 1200000
#define NUM_GRAPHS_C 64
#define D_C 64
#define BN_EPS_C 1e-5f

typedef unsigned short u16;
typedef unsigned int u32;

__device__ __forceinline__ u16 f2bf(float f) {  // RTNE
    u32 x = __float_as_uint(f);
    x += 0x7fffu + ((x >> 16) & 1u);
    return (u16)(x >> 16);
}
__device__ __forceinline__ float bf2f(u16 u) {
    return __uint_as_float(((u32)u) << 16);
}

// ----------------------------- degree count ------------------------------
__global__ void k_deg(const int* __restrict__ dst, int* __restrict__ deg) {
    int e = blockIdx.x * blockDim.x + threadIdx.x;
    if (e < N_EDGES_C) atomicAdd(&deg[dst[e]], 1);
}

// ----------------------------- scan (3 phase) ----------------------------
__global__ void k_scan_a(const int* __restrict__ deg, int* __restrict__ bsum) {
    int t = threadIdx.x;
    int i0 = blockIdx.x * 1024 + t * 4;
    int s = 0;
#pragma unroll
    for (int k = 0; k < 4; ++k) { int i = i0 + k; if (i < N_NODES_C) s += deg[i]; }
    __shared__ int sm[256];
    sm[t] = s; __syncthreads();
    for (int off = 128; off > 0; off >>= 1) {
        if (t < off) sm[t] += sm[t + off];
        __syncthreads();
    }
    if (t == 0) bsum[blockIdx.x] = sm[0];
}

__global__ void k_scan_b(const int* __restrict__ bsum, int* __restrict__ bscan, int nb) {
    int t = threadIdx.x;
    __shared__ int sm[128];
    int v = (t < nb) ? bsum[t] : 0;
    sm[t] = v; __syncthreads();
    for (int off = 1; off < 128; off <<= 1) {
        int x = (t >= off) ? sm[t - off] : 0;
        __syncthreads();
        sm[t] += x;
        __syncthreads();
    }
    if (t < nb) bscan[t] = sm[t] - v;  // exclusive
}

__global__ void k_scan_c(const int* __restrict__ deg, const int* __restrict__ bscan,
                         int* __restrict__ rowptr, int* __restrict__ cursor,
                         float* __restrict__ dinv) {
    int t = threadIdx.x;
    int i0 = blockIdx.x * 1024 + t * 4;
    int d[4]; int s = 0;
#pragma unroll
    for (int k = 0; k < 4; ++k) { int i = i0 + k; d[k] = (i < N_NODES_C) ? deg[i] : 0; s += d[k]; }
    __shared__ int sm[256];
    sm[t] = s; __syncthreads();
    for (int off = 1; off < 256; off <<= 1) {
        int x = (t >= off) ? sm[t - off] : 0;
        __syncthreads();
        sm[t] += x;
        __syncthreads();
    }
    int ex = sm[t] - s + bscan[blockIdx.x];
#pragma unroll
    for (int k = 0; k < 4; ++k) {
        int i = i0 + k;
        if (i < N_NODES_C) {
            rowptr[i] = ex;
            cursor[i] = ex;
            dinv[i] = rsqrtf((float)(d[k] + 1));  // +1 self-loop
            ex += d[k];
        }
    }
    if (blockIdx.x == 0 && t == 0) rowptr[N_NODES_C] = N_EDGES_C;
}

// ----------------------------- scatter to CSR ----------------------------
// Stores (src, dinv[src]*dinv[dst]) so gather needs no final scale.
__global__ void k_scatter(const int* __restrict__ src, const int* __restrict__ dst,
                          int* __restrict__ cursor, const float* __restrict__ dinv,
                          int2* __restrict__ colw) {
    int e = blockIdx.x * blockDim.x + threadIdx.x;
    if (e < N_EDGES_C) {
        int s = src[e], d = dst[e];
        int pos = atomicAdd(&cursor[d], 1);
        float w = dinv[s] * dinv[d];
        colw[pos] = make_int2(s, __float_as_int(w));
    }
}

// ----------------------------- GEMM [N,64]x[64,64] -> bf16 ----------------
__global__ void k_gemm64(const float* __restrict__ X, const float* __restrict__ W,
                         u16* __restrict__ T) {
    int lane = threadIdx.x & 63;
    int wave = blockIdx.x * (blockDim.x >> 6) + (threadIdx.x >> 6);
    int nwaves = gridDim.x * (blockDim.x >> 6);
    float Wc[64];
#pragma unroll
    for (int k = 0; k < 64; ++k) Wc[k] = W[k * 64 + lane];
    const float4* X4 = (const float4*)X;
    for (int r0 = wave * 4; r0 < N_NODES_C; r0 += nwaves * 4) {
        float a0 = 0.f, a1 = 0.f, a2 = 0.f, a3 = 0.f;
#pragma unroll
        for (int kq = 0; kq < 16; ++kq) {
            float4 q0 = X4[(size_t)(r0 + 0) * 16 + kq];
            float4 q1 = X4[(size_t)(r0 + 1) * 16 + kq];
            float4 q2 = X4[(size_t)(r0 + 2) * 16 + kq];
            float4 q3 = X4[(size_t)(r0 + 3) * 16 + kq];
            a0 = fmaf(q0.x, Wc[4 * kq + 0], a0); a0 = fmaf(q0.y, Wc[4 * kq + 1], a0);
            a0 = fmaf(q0.z, Wc[4 * kq + 2], a0); a0 = fmaf(q0.w, Wc[4 * kq + 3], a0);
            a1 = fmaf(q1.x, Wc[4 * kq + 0], a1); a1 = fmaf(q1.y, Wc[4 * kq + 1], a1);
            a1 = fmaf(q1.z, Wc[4 * kq + 2], a1); a1 = fmaf(q1.w, Wc[4 * kq + 3], a1);
            a2 = fmaf(q2.x, Wc[4 * kq + 0], a2); a2 = fmaf(q2.y, Wc[4 * kq + 1], a2);
            a2 = fmaf(q2.z, Wc[4 * kq + 2], a2); a2 = fmaf(q2.w, Wc[4 * kq + 3], a2);
            a3 = fmaf(q3.x, Wc[4 * kq + 0], a3); a3 = fmaf(q3.y, Wc[4 * kq + 1], a3);
            a3 = fmaf(q3.z, Wc[4 * kq + 2], a3); a3 = fmaf(q3.w, Wc[4 * kq + 3], a3);
        }
        T[(size_t)(r0 + 0) * 64 + lane] = f2bf(a0);
        T[(size_t)(r0 + 1) * 64 + lane] = f2bf(a1);
        T[(size_t)(r0 + 2) * 64 + lane] = f2bf(a2);
        T[(size_t)(r0 + 3) * 64 + lane] = f2bf(a3);
    }
}

// ----------------------------- gather layer 1 -----------------------------
// One wave per node. lane = feature. unroll-8 edge loop for MLP.
__global__ void __launch_bounds__(256) k_gather1(
        const u16* __restrict__ T, const int2* __restrict__ colw,
        const int* __restrict__ rowptr, const float* __restrict__ dinv,
        const float* __restrict__ b, const float* __restrict__ g,
        const float* __restrict__ be, const float* __restrict__ m,
        const float* __restrict__ v, float* __restrict__ A) {
    int lane = threadIdx.x & 63;
    int r = __builtin_amdgcn_readfirstlane(blockIdx.x * 4 + (threadIdx.x >> 6));
    if (r >= N_NODES_C) return;
    float sc = g[lane] * rsqrtf(v[lane] + BN_EPS_C);
    float c0 = (b[lane] - m[lane]) * sc + be[lane];
    float dr = dinv[r];
    float acc = bf2f(T[(size_t)r * 64 + lane]) * dr * dr;  // self-loop
    int jb = rowptr[r], je = rowptr[r + 1];
    for (int j = jb; j < je; j += 8) {
        int idx[8]; float w[8];
#pragma unroll
        for (int k = 0; k < 8; ++k) {
            int jj = (j + k < je) ? (j + k) : jb;
            int2 e = colw[jj];
            idx[k] = e.x;
            w[k] = (j + k < je) ? __int_as_float(e.y) : 0.f;
        }
        float t[8];
#pragma unroll
        for (int k = 0; k < 8; ++k) t[k] = bf2f(T[(size_t)idx[k] * 64 + lane]);
#pragma unroll
        for (int k = 0; k < 8; ++k) acc = fmaf(t[k], w[k], acc);
    }
    A[(size_t)r * 64 + lane] = fmaxf(fmaf(acc, sc, c0), 0.f);
}

// ----------------------------- gather layer 2 + pool ----------------------
__global__ void __launch_bounds__(256) k_gather2(
        const u16* __restrict__ T, const int2* __restrict__ colw,
        const int* __restrict__ rowptr, const float* __restrict__ dinv,
        const float* __restrict__ b, const float* __restrict__ g,
        const float* __restrict__ be, const float* __restrict__ m,
        const float* __restrict__ v, const int* __restrict__ batch,
        float* __restrict__ pooled) {
    int lane = threadIdx.x & 63;
    int r = __builtin_amdgcn_readfirstlane(blockIdx.x * 4 + (threadIdx.x >> 6));
    if (r >= N_NODES_C) return;
    float sc = g[lane] * rsqrtf(v[lane] + BN_EPS_C);
    float c0 = (b[lane] - m[lane]) * sc + be[lane];
    float dr = dinv[r];
    float acc = bf2f(T[(size_t)r * 64 + lane]) * dr * dr;
    int jb = rowptr[r], je = rowptr[r + 1];
    for (int j = jb; j < je; j += 8) {
        int idx[8]; float w[8];
#pragma unroll
        for (int k = 0; k < 8; ++k) {
            int jj = (j + k < je) ? (j + k) : jb;
            int2 e = colw[jj];
            idx[k] = e.x;
            w[k] = (j + k < je) ? __int_as_float(e.y) : 0.f;
        }
        float t[8];
#pragma unroll
        for (int k = 0; k < 8; ++k) t[k] = bf2f(T[(size_t)idx[k] * 64 + lane]);
#pragma unroll
        for (int k = 0; k < 8; ++k) acc = fmaf(t[k], w[k], acc);
    }
    float val = fmaxf(fmaf(acc, sc, c0), 0.f);
    int gid = batch[r];
    atomicAdd(&pooled[gid * 64 + lane], val);
}

// ----------------------------- classifier --------------------------------
// Graph counts recovered by binary search on sorted `batch` (no atomics).
__global__ void k_final(const float* __restrict__ pooled, const int* __restrict__ batch,
                        const float* __restrict__ Wc, const float* __restrict__ bc,
                        float* __restrict__ out) {
    int lane = threadIdx.x & 63;
    int wv = threadIdx.x >> 6;
    for (int gi = wv; gi < NUM_GRAPHS_C; gi += 2) {
        // ub: first index with batch > gi ; lb: first index with batch >= gi
        int lo = 0, hi = N_NODES_C;
        while (lo < hi) { int mid = (lo + hi) >> 1; if (batch[mid] > gi) hi = mid; else lo = mid + 1; }
        int ub = lo;
        lo = 0; hi = N_NODES_C;
        while (lo < hi) { int mid = (lo + hi) >> 1; if (batch[mid] >= gi) hi = mid; else lo = mid + 1; }
        int cnt = ub - lo;
        float inv = 1.0f / fmaxf((float)cnt, 1.0f);
        float p = pooled[gi * 64 + lane] * inv;
        float v0 = p * Wc[lane * 2 + 0];
        float v1 = p * Wc[lane * 2 + 1];
        for (int off = 32; off > 0; off >>= 1) {
            v0 += __shfl_down(v0, off);
            v1 += __shfl_down(v1, off);
        }
        if (lane == 0) {
            out[gi * 2 + 0] = v0 + bc[0];
            out[gi * 2 + 1] = v1 + bc[1];
        }
    }
}

extern "C" void kernel_launch(void* const* d_in, const int* in_sizes, int n_in,
                              void* d_out, int out_size, void* d_ws, size_t ws_size,
                              hipStream_t stream) {
    const float* x    = (const float*)d_in[0];
    const int*   ei   = (const int*)d_in[1];
    const int*   batch= (const int*)d_in[2];
    const float* W1 = (const float*)d_in[3];
    const float* b1 = (const float*)d_in[4];
    const float* g1 = (const float*)d_in[5];
    const float* be1= (const float*)d_in[6];
    const float* m1 = (const float*)d_in[7];
    const float* v1 = (const float*)d_in[8];
    const float* W2 = (const float*)d_in[9];
    const float* b2 = (const float*)d_in[10];
    const float* g2 = (const float*)d_in[11];
    const float* be2= (const float*)d_in[12];
    const float* m2 = (const float*)d_in[13];
    const float* v2 = (const float*)d_in[14];
    const float* Wc = (const float*)d_in[15];
    const float* bc = (const float*)d_in[16];
    float* out = (float*)d_out;

    char* ws = (char*)d_ws;
    size_t off = 0;
    auto alloc = [&](size_t bytes) {
        size_t o = off;
        off = (off + bytes + 511) & ~(size_t)511;
        return o;
    };
    size_t o_deg   = alloc((size_t)N_NODES_C * 4);
    size_t o_pool  = alloc((size_t)NUM_GRAPHS_C * D_C * 4);
    size_t zero_bytes = off;  // [deg | pooled] zeroed each call
    size_t o_rowptr= alloc((size_t)(N_NODES_C + 1) * 4);
    size_t o_cur   = alloc((size_t)N_NODES_C * 4);
    size_t o_dinv  = alloc((size_t)N_NODES_C * 4);
    size_t o_bsum  = alloc(128 * 4);
    size_t o_bscan = alloc(128 * 4);
    size_t o_colw  = alloc((size_t)N_EDGES_C * 8);
    size_t o_t     = alloc((size_t)N_NODES_C * D_C * 2);  // bf16
    size_t o_a     = alloc((size_t)N_NODES_C * D_C * 4);
    (void)ws_size; (void)in_sizes; (void)n_in; (void)out_size;

    int*   deg    = (int*)(ws + o_deg);
    float* pooled = (float*)(ws + o_pool);
    int*   rowptr = (int*)(ws + o_rowptr);
    int*   cursor = (int*)(ws + o_cur);
    float* dinv   = (float*)(ws + o_dinv);
    int*   bsum   = (int*)(ws + o_bsum);
    int*   bscan  = (int*)(ws + o_bscan);
    int2*  colw   = (int2*)(ws + o_colw);
    u16*   T      = (u16*)(ws + o_t);
    float* A      = (float*)(ws + o_a);

    const int* srcp = ei;
    const int* dstp = ei + N_EDGES_C;

    hipMemsetAsync(ws, 0, zero_bytes, stream);

    int eblocks = (N_EDGES_C + 255) / 256;
    int nb = (N_NODES_C + 1023) / 1024;  // 98
    int gblocks = (N_NODES_C + 3) / 4;   // 1 node per wave, 4 waves per block
    k_deg<<<eblocks, 256, 0, stream>>>(dstp, deg);
    k_scan_a<<<nb, 256, 0, stream>>>(deg, bsum);
    k_scan_b<<<1, 128, 0, stream>>>(bsum, bscan, nb);
    k_scan_c<<<nb, 256, 0, stream>>>(deg, bscan, rowptr, cursor, dinv);
    k_scatter<<<eblocks, 256, 0, stream>>>(srcp, dstp, cursor, dinv, colw);

    k_gemm64<<<1040, 256, 0, stream>>>(x, W1, T);
    k_gather1<<<gblocks, 256, 0, stream>>>(T, colw, rowptr, dinv, b1, g1, be1, m1, v1, A);
    k_gemm64<<<1040, 256, 0, stream>>>(A, W2, T);
    k_gather2<<<gblocks, 256, 0, stream>>>(T, colw, rowptr, dinv, b2, g2, be2, m2, v2,
                                           batch, pooled);
    k_final<<<1, 128, 0, stream>>>(pooled, batch, Wc, bc, out);
}

// Round 3
// 498.285 us; speedup vs baseline: 1.4662x; 1.4662x over previous
//
#include <hip/hip_runtime.h>

#define N_NODES_C 100000
#define N_EDGES_C 1200000
#define NUM_GRAPHS_C 64
#define D_C 64
#define BN_EPS_C 1e-5f

typedef unsigned short u16;
typedef unsigned int u32;

__device__ __forceinline__ u16 f2bf(float f) {  // RTNE
    u32 x = __float_as_uint(f);
    x += 0x7fffu + ((x >> 16) & 1u);
    return (u16)(x >> 16);
}
__device__ __forceinline__ float bf2f(u16 u) {
    return __uint_as_float(((u32)u) << 16);
}

// ----------------------------- degree count ------------------------------
__global__ void k_deg(const int* __restrict__ dst, int* __restrict__ deg) {
    int e = blockIdx.x * blockDim.x + threadIdx.x;
    if (e < N_EDGES_C) atomicAdd(&deg[dst[e]], 1);
}

// ----------------------------- scan (3 phase) ----------------------------
__global__ void k_scan_a(const int* __restrict__ deg, int* __restrict__ bsum) {
    int t = threadIdx.x;
    int i0 = blockIdx.x * 1024 + t * 4;
    int s = 0;
#pragma unroll
    for (int k = 0; k < 4; ++k) { int i = i0 + k; if (i < N_NODES_C) s += deg[i]; }
    __shared__ int sm[256];
    sm[t] = s; __syncthreads();
    for (int off = 128; off > 0; off >>= 1) {
        if (t < off) sm[t] += sm[t + off];
        __syncthreads();
    }
    if (t == 0) bsum[blockIdx.x] = sm[0];
}

__global__ void k_scan_b(const int* __restrict__ bsum, int* __restrict__ bscan, int nb) {
    int t = threadIdx.x;
    __shared__ int sm[128];
    int v = (t < nb) ? bsum[t] : 0;
    sm[t] = v; __syncthreads();
    for (int off = 1; off < 128; off <<= 1) {
        int x = (t >= off) ? sm[t - off] : 0;
        __syncthreads();
        sm[t] += x;
        __syncthreads();
    }
    if (t < nb) bscan[t] = sm[t] - v;  // exclusive
}

__global__ void k_scan_c(const int* __restrict__ deg, const int* __restrict__ bscan,
                         int* __restrict__ rowptr, int* __restrict__ cursor,
                         float* __restrict__ dinv) {
    int t = threadIdx.x;
    int i0 = blockIdx.x * 1024 + t * 4;
    int d[4]; int s = 0;
#pragma unroll
    for (int k = 0; k < 4; ++k) { int i = i0 + k; d[k] = (i < N_NODES_C) ? deg[i] : 0; s += d[k]; }
    __shared__ int sm[256];
    sm[t] = s; __syncthreads();
    for (int off = 1; off < 256; off <<= 1) {
        int x = (t >= off) ? sm[t - off] : 0;
        __syncthreads();
        sm[t] += x;
        __syncthreads();
    }
    int ex = sm[t] - s + bscan[blockIdx.x];
#pragma unroll
    for (int k = 0; k < 4; ++k) {
        int i = i0 + k;
        if (i < N_NODES_C) {
            rowptr[i] = ex;
            cursor[i] = ex;
            dinv[i] = rsqrtf((float)(d[k] + 1));  // +1 self-loop
            ex += d[k];
        }
    }
    if (blockIdx.x == 0 && t == 0) rowptr[N_NODES_C] = N_EDGES_C;
}

// ----------------------------- scatter to CSR ----------------------------
// Stores (src, dinv[src]*dinv[dst]) so gather needs no final scale.
__global__ void k_scatter(const int* __restrict__ src, const int* __restrict__ dst,
                          int* __restrict__ cursor, const float* __restrict__ dinv,
                          int2* __restrict__ colw) {
    int e = blockIdx.x * blockDim.x + threadIdx.x;
    if (e < N_EDGES_C) {
        int s = src[e], d = dst[e];
        int pos = atomicAdd(&cursor[d], 1);
        float w = dinv[s] * dinv[d];
        colw[pos] = make_int2(s, __float_as_int(w));
    }
}

// ----------------------------- GEMM [N,64]x[64,64] -> bf16 ----------------
__global__ void k_gemm64(const float* __restrict__ X, const float* __restrict__ W,
                         u16* __restrict__ T) {
    int lane = threadIdx.x & 63;
    int wave = blockIdx.x * (blockDim.x >> 6) + (threadIdx.x >> 6);
    int nwaves = gridDim.x * (blockDim.x >> 6);
    float Wc[64];
#pragma unroll
    for (int k = 0; k < 64; ++k) Wc[k] = W[k * 64 + lane];
    const float4* X4 = (const float4*)X;
    for (int r0 = wave * 4; r0 < N_NODES_C; r0 += nwaves * 4) {
        float a0 = 0.f, a1 = 0.f, a2 = 0.f, a3 = 0.f;
#pragma unroll
        for (int kq = 0; kq < 16; ++kq) {
            float4 q0 = X4[(size_t)(r0 + 0) * 16 + kq];
            float4 q1 = X4[(size_t)(r0 + 1) * 16 + kq];
            float4 q2 = X4[(size_t)(r0 + 2) * 16 + kq];
            float4 q3 = X4[(size_t)(r0 + 3) * 16 + kq];
            a0 = fmaf(q0.x, Wc[4 * kq + 0], a0); a0 = fmaf(q0.y, Wc[4 * kq + 1], a0);
            a0 = fmaf(q0.z, Wc[4 * kq + 2], a0); a0 = fmaf(q0.w, Wc[4 * kq + 3], a0);
            a1 = fmaf(q1.x, Wc[4 * kq + 0], a1); a1 = fmaf(q1.y, Wc[4 * kq + 1], a1);
            a1 = fmaf(q1.z, Wc[4 * kq + 2], a1); a1 = fmaf(q1.w, Wc[4 * kq + 3], a1);
            a2 = fmaf(q2.x, Wc[4 * kq + 0], a2); a2 = fmaf(q2.y, Wc[4 * kq + 1], a2);
            a2 = fmaf(q2.z, Wc[4 * kq + 2], a2); a2 = fmaf(q2.w, Wc[4 * kq + 3], a2);
            a3 = fmaf(q3.x, Wc[4 * kq + 0], a3); a3 = fmaf(q3.y, Wc[4 * kq + 1], a3);
            a3 = fmaf(q3.z, Wc[4 * kq + 2], a3); a3 = fmaf(q3.w, Wc[4 * kq + 3], a3);
        }
        T[(size_t)(r0 + 0) * 64 + lane] = f2bf(a0);
        T[(size_t)(r0 + 1) * 64 + lane] = f2bf(a1);
        T[(size_t)(r0 + 2) * 64 + lane] = f2bf(a2);
        T[(size_t)(r0 + 3) * 64 + lane] = f2bf(a3);
    }
}

// ----------------------------- gather (fused pair) ------------------------
// Persistent waves, grid-stride over node PAIRS (2r, 2r+1). CSR ranges of a
// pair are contiguous, so one flat 8-edge-batch loop feeds both accumulators
// via cndmask routing — no raggedness waste, 8 row-loads in flight per wave.
// LAYER2: also does the mean-pool atomic accumulation (POOL=true).
template <bool POOL>
__device__ __forceinline__ void gather_body(
        const u16* __restrict__ T, const int2* __restrict__ colw,
        const int* __restrict__ rowptr, const float* __restrict__ dinv,
        const float* __restrict__ b, const float* __restrict__ g,
        const float* __restrict__ be, const float* __restrict__ m,
        const float* __restrict__ v, const int* __restrict__ batch,
        float* __restrict__ A, float* __restrict__ pooled) {
    int lane = threadIdx.x & 63;
    int wave = blockIdx.x * 4 + (threadIdx.x >> 6);
    int nwaves = gridDim.x * 4;
    float sc = g[lane] * rsqrtf(v[lane] + BN_EPS_C);
    float c0 = (b[lane] - m[lane]) * sc + be[lane];
    const int npairs = N_NODES_C / 2;
    for (int base = wave; base < npairs; base += nwaves) {
        int rA = __builtin_amdgcn_readfirstlane(base * 2);
        int rB = rA + 1;
        int jbA = rowptr[rA];
        int jeA = rowptr[rB];
        int jeB = rowptr[rB + 1];
        float drA = dinv[rA], drB = dinv[rB];
        float accA = bf2f(T[(size_t)rA * 64 + lane]) * drA * drA;  // self-loops
        float accB = bf2f(T[(size_t)rB * 64 + lane]) * drB * drB;
        for (int j = jbA; j < jeB; j += 8) {
            int idx[8]; float wA[8], wB[8];
#pragma unroll
            for (int k = 0; k < 8; ++k) {
                int jj = (j + k < jeB) ? (j + k) : jbA;
                int2 e = colw[jj];
                float w = (j + k < jeB) ? __int_as_float(e.y) : 0.f;
                bool isB = (j + k >= jeA);
                wA[k] = isB ? 0.f : w;
                wB[k] = isB ? w : 0.f;
                idx[k] = e.x;
            }
            float t[8];
#pragma unroll
            for (int k = 0; k < 8; ++k) t[k] = bf2f(T[(size_t)idx[k] * 64 + lane]);
#pragma unroll
            for (int k = 0; k < 8; ++k) {
                accA = fmaf(t[k], wA[k], accA);
                accB = fmaf(t[k], wB[k], accB);
            }
        }
        float valA = fmaxf(fmaf(accA, sc, c0), 0.f);
        float valB = fmaxf(fmaf(accB, sc, c0), 0.f);
        if (POOL) {
            int gA = batch[rA], gB = batch[rB];
            if (gA == gB) {
                atomicAdd(&pooled[gA * 64 + lane], valA + valB);
            } else {
                atomicAdd(&pooled[gA * 64 + lane], valA);
                atomicAdd(&pooled[gB * 64 + lane], valB);
            }
        } else {
            A[(size_t)rA * 64 + lane] = valA;
            A[(size_t)rB * 64 + lane] = valB;
        }
    }
}

__global__ void __launch_bounds__(256) k_gather1(
        const u16* __restrict__ T, const int2* __restrict__ colw,
        const int* __restrict__ rowptr, const float* __restrict__ dinv,
        const float* __restrict__ b, const float* __restrict__ g,
        const float* __restrict__ be, const float* __restrict__ m,
        const float* __restrict__ v, float* __restrict__ A) {
    gather_body<false>(T, colw, rowptr, dinv, b, g, be, m, v, nullptr, A, nullptr);
}

__global__ void __launch_bounds__(256) k_gather2(
        const u16* __restrict__ T, const int2* __restrict__ colw,
        const int* __restrict__ rowptr, const float* __restrict__ dinv,
        const float* __restrict__ b, const float* __restrict__ g,
        const float* __restrict__ be, const float* __restrict__ m,
        const float* __restrict__ v, const int* __restrict__ batch,
        float* __restrict__ pooled) {
    gather_body<true>(T, colw, rowptr, dinv, b, g, be, m, v, batch, nullptr, pooled);
}

// ----------------------------- classifier --------------------------------
// Lane-parallel binary search (lane gi finds upper bound of graph gi in the
// sorted batch array); counts from adjacent boundaries; dot from padded LDS.
__global__ void k_final(const float* __restrict__ pooled, const int* __restrict__ batch,
                        const float* __restrict__ Wc, const float* __restrict__ bc,
                        float* __restrict__ out) {
    __shared__ float sp[64 * 65];
    __shared__ int sub[64];
    int t = threadIdx.x;  // 256 threads
    for (int i = t; i < 4096; i += 256) sp[(i >> 6) * 65 + (i & 63)] = pooled[i];
    if (t < 64) {
        int lo = 0, hi = N_NODES_C;
        while (lo < hi) { int mid = (lo + hi) >> 1; if (batch[mid] > t) hi = mid; else lo = mid + 1; }
        sub[t] = lo;  // first index with batch > t
    }
    __syncthreads();
    if (t < 64) {
        int gi = t;
        int lb = gi ? sub[gi - 1] : 0;
        int cnt = sub[gi] - lb;
        float inv = 1.0f / fmaxf((float)cnt, 1.0f);
        float a0 = 0.f, a1 = 0.f;
#pragma unroll 8
        for (int f = 0; f < 64; ++f) {
            float p = sp[gi * 65 + f];
            a0 = fmaf(p, Wc[f * 2 + 0], a0);
            a1 = fmaf(p, Wc[f * 2 + 1], a1);
        }
        out[gi * 2 + 0] = a0 * inv + bc[0];
        out[gi * 2 + 1] = a1 * inv + bc[1];
    }
}

extern "C" void kernel_launch(void* const* d_in, const int* in_sizes, int n_in,
                              void* d_out, int out_size, void* d_ws, size_t ws_size,
                              hipStream_t stream) {
    const float* x    = (const float*)d_in[0];
    const int*   ei   = (const int*)d_in[1];
    const int*   batch= (const int*)d_in[2];
    const float* W1 = (const float*)d_in[3];
    const float* b1 = (const float*)d_in[4];
    const float* g1 = (const float*)d_in[5];
    const float* be1= (const float*)d_in[6];
    const float* m1 = (const float*)d_in[7];
    const float* v1 = (const float*)d_in[8];
    const float* W2 = (const float*)d_in[9];
    const float* b2 = (const float*)d_in[10];
    const float* g2 = (const float*)d_in[11];
    const float* be2= (const float*)d_in[12];
    const float* m2 = (const float*)d_in[13];
    const float* v2 = (const float*)d_in[14];
    const float* Wc = (const float*)d_in[15];
    const float* bc = (const float*)d_in[16];
    float* out = (float*)d_out;

    char* ws = (char*)d_ws;
    size_t off = 0;
    auto alloc = [&](size_t bytes) {
        size_t o = off;
        off = (off + bytes + 511) & ~(size_t)511;
        return o;
    };
    size_t o_deg   = alloc((size_t)N_NODES_C * 4);
    size_t o_pool  = alloc((size_t)NUM_GRAPHS_C * D_C * 4);
    size_t zero_bytes = off;  // [deg | pooled] zeroed each call
    size_t o_rowptr= alloc((size_t)(N_NODES_C + 1) * 4);
    size_t o_cur   = alloc((size_t)N_NODES_C * 4);
    size_t o_dinv  = alloc((size_t)N_NODES_C * 4);
    size_t o_bsum  = alloc(128 * 4);
    size_t o_bscan = alloc(128 * 4);
    size_t o_colw  = alloc((size_t)N_EDGES_C * 8);
    size_t o_t     = alloc((size_t)N_NODES_C * D_C * 2);  // bf16
    size_t o_a     = alloc((size_t)N_NODES_C * D_C * 4);
    (void)ws_size; (void)in_sizes; (void)n_in; (void)out_size;

    int*   deg    = (int*)(ws + o_deg);
    float* pooled = (float*)(ws + o_pool);
    int*   rowptr = (int*)(ws + o_rowptr);
    int*   cursor = (int*)(ws + o_cur);
    float* dinv   = (float*)(ws + o_dinv);
    int*   bsum   = (int*)(ws + o_bsum);
    int*   bscan  = (int*)(ws + o_bscan);
    int2*  colw   = (int2*)(ws + o_colw);
    u16*   T      = (u16*)(ws + o_t);
    float* A      = (float*)(ws + o_a);

    const int* srcp = ei;
    const int* dstp = ei + N_EDGES_C;

    hipMemsetAsync(ws, 0, zero_bytes, stream);

    int eblocks = (N_EDGES_C + 255) / 256;
    int nb = (N_NODES_C + 1023) / 1024;  // 98
    int gblocks = 2048;  // 8192 persistent waves = full residency (256 CU x 32)
    k_deg<<<eblocks, 256, 0, stream>>>(dstp, deg);
    k_scan_a<<<nb, 256, 0, stream>>>(deg, bsum);
    k_scan_b<<<1, 128, 0, stream>>>(bsum, bscan, nb);
    k_scan_c<<<nb, 256, 0, stream>>>(deg, bscan, rowptr, cursor, dinv);
    k_scatter<<<eblocks, 256, 0, stream>>>(srcp, dstp, cursor, dinv, colw);

    k_gemm64<<<1040, 256, 0, stream>>>(x, W1, T);
    k_gather1<<<gblocks, 256, 0, stream>>>(T, colw, rowptr, dinv, b1, g1, be1, m1, v1, A);
    k_gemm64<<<1040, 256, 0, stream>>>(A, W2, T);
    k_gather2<<<gblocks, 256, 0, stream>>>(T, colw, rowptr, dinv, b2, g2, be2, m2, v2,
                                           batch, pooled);
    k_final<<<1, 256, 0, stream>>>(pooled, batch, Wc, bc, out);
}